// Round 2
// baseline (12248.933 us; speedup 1.0000x reference)
//
#include <hip/hip_runtime.h>
#include <hip/hip_bf16.h>
#include <cstdint>
#include <cstddef>

#define B_   64
#define T_   300
#define DIN_ 768
#define D_   300
#define E_   8
#define H_   4
#define HS_  16
#define NTOK (B_*T_)   // 19200

// ---------------------------------------------------------------------------
// K0: bp[o] = -sum_d wh_bias[d] * wh_W[o,d]
// ---------------------------------------------------------------------------
__global__ void biasproj_kernel(const float* __restrict__ wh_bias,
                                const float* __restrict__ wh_W,
                                float* __restrict__ bp) {
  int o = blockIdx.x * blockDim.x + threadIdx.x;
  if (o >= D_) return;
  float acc = 0.f;
  const float* row = wh_W + (size_t)o * DIN_;
  for (int d = 0; d < DIN_; ++d) acc += wh_bias[d] * row[d];
  bp[o] = -acc;
}

// ---------------------------------------------------------------------------
// Generic tiled GEMM:  C[M,N] = A[M,K] * B[N,K]^T + bias
// 64x64 tile, TK=16, 256 threads, 4x4 per thread. All fp32.
// ---------------------------------------------------------------------------
__global__ __launch_bounds__(256) void gemm_nt(
    const float* __restrict__ A, const float* __restrict__ Bm,
    const float* __restrict__ biasf, float* __restrict__ C,
    int M, int N, int K) {
  __shared__ float As[64][17];
  __shared__ float Bs[64][17];
  const int bm = blockIdx.y * 64, bn = blockIdx.x * 64;
  const int tid = threadIdx.x;
  const int tx = tid & 15, ty = tid >> 4;
  float acc[4][4] = {};
  for (int k0 = 0; k0 < K; k0 += 16) {
    const int r  = tid >> 2;
    const int c4 = (tid & 3) * 4;
    {
      int gr = bm + r;
      #pragma unroll
      for (int u = 0; u < 4; ++u) {
        int gc = k0 + c4 + u;
        As[r][c4 + u] = (gr < M && gc < K) ? A[(size_t)gr * K + gc] : 0.f;
      }
    }
    {
      int gr = bn + r;
      #pragma unroll
      for (int u = 0; u < 4; ++u) {
        int gc = k0 + c4 + u;
        Bs[r][c4 + u] = (gr < N && gc < K) ? Bm[(size_t)gr * K + gc] : 0.f;
      }
    }
    __syncthreads();
    #pragma unroll
    for (int kk = 0; kk < 16; ++kk) {
      float a[4], b[4];
      #pragma unroll
      for (int i = 0; i < 4; ++i) a[i] = As[ty * 4 + i][kk];
      #pragma unroll
      for (int j = 0; j < 4; ++j) b[j] = Bs[tx * 4 + j][kk];
      #pragma unroll
      for (int i = 0; i < 4; ++i)
        #pragma unroll
        for (int j = 0; j < 4; ++j) acc[i][j] += a[i] * b[j];
    }
    __syncthreads();
  }
  #pragma unroll
  for (int i = 0; i < 4; ++i) {
    int rr = bm + ty * 4 + i;
    if (rr >= M) continue;
    #pragma unroll
    for (int j = 0; j < 4; ++j) {
      int cc = bn + tx * 4 + j;
      if (cc >= N) continue;
      float v = acc[i][j];
      if (biasf) v += biasf[cc];
      C[(size_t)rr * N + cc] = v;
    }
  }
}

// ---------------------------------------------------------------------------
// Attention: one 64-thread block per (b,t). 16 lanes per head.
// q,k,v: [NTOK, 64] fp32, col = h*16+hs. att: [NTOK, 64].
// ---------------------------------------------------------------------------
__global__ __launch_bounds__(64) void attn_kernel(
    const float* __restrict__ q, const float* __restrict__ k,
    const float* __restrict__ v, float* __restrict__ att) {
  const int bt = blockIdx.x;
  const int b = bt / T_, t = bt % T_;
  const int lane = threadIdx.x;
  const int h = lane >> 4, li = lane & 15;
  __shared__ float p[H_][304];
  __shared__ float qs[64];
  qs[lane] = q[(size_t)bt * 64 + lane];
  __syncthreads();
  const float scale = rsqrtf((float)D_);
  const float* kbase = k + (size_t)b * T_ * 64 + h * 16;
  float mmax = -1e30f;
  for (int s = li; s <= t; s += 16) {
    const float* kr = kbase + (size_t)s * 64;
    float acc = 0.f;
    #pragma unroll
    for (int d = 0; d < 16; ++d) acc += qs[h * 16 + d] * kr[d];
    acc *= scale;
    p[h][s] = acc;
    mmax = fmaxf(mmax, acc);
  }
  #pragma unroll
  for (int m = 8; m >= 1; m >>= 1) mmax = fmaxf(mmax, __shfl_xor(mmax, m, 16));
  float lsum = 0.f;
  for (int s = li; s <= t; s += 16) {
    float e = __expf(p[h][s] - mmax);
    p[h][s] = e;
    lsum += e;
  }
  #pragma unroll
  for (int m = 8; m >= 1; m >>= 1) lsum += __shfl_xor(lsum, m, 16);
  const float inv = 1.0f / lsum;
  const float* vcol = v + (size_t)b * T_ * 64 + h * 16 + li;
  float o = 0.f;
  for (int s = 0; s <= t; ++s) o += p[h][s] * vcol[(size_t)s * 64];
  att[(size_t)bt * 64 + lane] = o * inv;
}

// ---------------------------------------------------------------------------
// logits[n,e] = sum_d xa[n,d] * w_gate[d,e]
// ---------------------------------------------------------------------------
__global__ void logits_kernel(const float* __restrict__ xa,
                              const float* __restrict__ w_gate,
                              float* __restrict__ logits) {
  int idx = blockIdx.x * blockDim.x + threadIdx.x;
  if (idx >= NTOK * E_) return;
  int n = idx >> 3, e = idx & 7;
  const float* xr = xa + (size_t)n * D_;
  float acc = 0.f;
  for (int d = 0; d < D_; ++d) acc += xr[d] * w_gate[(size_t)d * E_ + e];
  logits[idx] = acc;
}

// ---------------------------------------------------------------------------
// top-4 sparse softmax per token
// ---------------------------------------------------------------------------
__global__ void gate_kernel(const float* __restrict__ logits,
                            float* __restrict__ gprob) {
  int n = blockIdx.x * blockDim.x + threadIdx.x;
  if (n >= NTOK) return;
  float l[E_];
  #pragma unroll
  for (int e = 0; e < E_; ++e) l[e] = logits[(size_t)n * E_ + e];
  bool sel[E_] = {false, false, false, false, false, false, false, false};
  for (int kk = 0; kk < E_ / 2; ++kk) {
    int bi = -1; float bv = -1e38f;
    #pragma unroll
    for (int e = 0; e < E_; ++e)
      if (!sel[e] && l[e] > bv) { bv = l[e]; bi = e; }
    sel[bi] = true;
  }
  float mx = -1e38f;
  #pragma unroll
  for (int e = 0; e < E_; ++e) if (sel[e]) mx = fmaxf(mx, l[e]);
  float s = 0.f, pp[E_];
  #pragma unroll
  for (int e = 0; e < E_; ++e) {
    pp[e] = sel[e] ? __expf(l[e] - mx) : 0.f;
    s += pp[e];
  }
  float inv = 1.0f / s;
  #pragma unroll
  for (int e = 0; e < E_; ++e) gprob[(size_t)n * E_ + e] = pp[e] * inv;
}

// ---------------------------------------------------------------------------
// Fused experts: 16-token tile per block, 256 threads.
// LDS transposed [d][tok] so activation reads broadcast across lanes.
// For each expert: h = relu(W1 xa + b1) in LDS, eo = W2 h + b2 in regs,
// accumulate gsum += g*eo, esum += eo. out = gsum*esum (fp32).
// ---------------------------------------------------------------------------
__global__ __launch_bounds__(256) void expert_kernel(
    const float* __restrict__ xa, const float* __restrict__ gprob,
    const float* __restrict__ W1, const float* __restrict__ b1,
    const float* __restrict__ W2, const float* __restrict__ b2,
    float* __restrict__ out) {
  __shared__ float xs[D_][16];    // [d][tok]
  __shared__ float hsm[600][16];  // [j][tok]
  const int tid = threadIdx.x;
  const int tok0 = blockIdx.x * 16;
  const int tokA = tid & 15, jj = tid >> 4;   // stage A map (16 tokens x 16 rows-at-a-time)
  const int tokB = tid >> 4, oc = tid & 15;   // stage B map (16 tokens x 16 cols-at-a-time)
  for (int i = tid; i < 16 * D_; i += 256) {
    int r = i / D_, c = i % D_;
    xs[c][r] = xa[(size_t)(tok0 + r) * D_ + c];
  }
  float gsum[19], esum[19];
  #pragma unroll
  for (int i = 0; i < 19; ++i) { gsum[i] = 0.f; esum[i] = 0.f; }
  __syncthreads();

  for (int e = 0; e < E_; ++e) {
    const float* w1 = W1 + (size_t)e * 600 * D_;
    // stage A: hsm[j][tok] = relu(dot(xs[:,tok], w1[j,:]) + b1)
    for (int j0 = 0; j0 < 600; j0 += 16) {
      int j = j0 + jj;
      if (j < 600) {
        const float* wr = w1 + (size_t)j * D_;   // 1200B-aligned row
        float acc = 0.f;
        for (int d = 0; d < D_; d += 4) {
          float4 wv = *(const float4*)&wr[d];
          acc += xs[d][tokA]     * wv.x;
          acc += xs[d + 1][tokA] * wv.y;
          acc += xs[d + 2][tokA] * wv.z;
          acc += xs[d + 3][tokA] * wv.w;
        }
        acc += b1[(size_t)e * 600 + j];
        hsm[j][tokA] = fmaxf(acc, 0.f);
      }
    }
    __syncthreads();
    // stage B: thread owns (tokB, o = oc+16*i) for i in [0,19)
    const float* w2 = W2 + (size_t)e * D_ * 600;
    const float g = gprob[(size_t)(tok0 + tokB) * E_ + e];
    #pragma unroll
    for (int i = 0; i < 19; ++i) {
      int o = oc + 16 * i;
      if (o < D_) {
        const float* wr = w2 + (size_t)o * 600;  // 2400B-aligned row
        float acc = 0.f;
        for (int hh = 0; hh < 600; hh += 4) {
          float4 wv = *(const float4*)&wr[hh];
          acc += hsm[hh][tokB]     * wv.x;
          acc += hsm[hh + 1][tokB] * wv.y;
          acc += hsm[hh + 2][tokB] * wv.z;
          acc += hsm[hh + 3][tokB] * wv.w;
        }
        acc += b2[(size_t)e * D_ + o];
        gsum[i] += g * acc;
        esum[i] += acc;
      }
    }
    __syncthreads();
  }
  #pragma unroll
  for (int i = 0; i < 19; ++i) {
    int o = oc + 16 * i;
    if (o < D_)
      out[(size_t)(tok0 + tokB) * D_ + o] = gsum[i] * esum[i];
  }
}

// ---------------------------------------------------------------------------
extern "C" void kernel_launch(void* const* d_in, const int* in_sizes, int n_in,
                              void* d_out, int out_size, void* d_ws, size_t ws_size,
                              hipStream_t stream) {
  const float* x       = (const float*)d_in[0];
  const float* wh_bias = (const float*)d_in[1];
  const float* wh_W    = (const float*)d_in[2];
  const float* Wq      = (const float*)d_in[3];
  const float* Wk      = (const float*)d_in[4];
  const float* Wv      = (const float*)d_in[5];
  const float* proj_W  = (const float*)d_in[6];
  const float* proj_b  = (const float*)d_in[7];
  const float* exp_W1  = (const float*)d_in[8];
  const float* exp_b1  = (const float*)d_in[9];
  const float* exp_W2  = (const float*)d_in[10];
  const float* exp_b2  = (const float*)d_in[11];
  const float* w_gate  = (const float*)d_in[12];

  char* ws = (char*)d_ws;
  size_t off = 0;
  auto alloc = [&](size_t bytes) { void* p = ws + off; off += (bytes + 511) & ~(size_t)511; return p; };
  float* bp     = (float*)alloc(D_ * 4);
  float* xw     = (float*)alloc((size_t)NTOK * D_ * 4);   // reused for att/logits/gprob later
  float* qb     = (float*)alloc((size_t)NTOK * 64 * 4);
  float* kb     = (float*)alloc((size_t)NTOK * 64 * 4);
  float* vb     = (float*)alloc((size_t)NTOK * 64 * 4);
  float* xa     = (float*)alloc((size_t)NTOK * D_ * 4);
  // alias region: xw is dead after QKV; att/logits/gprob fit inside its 23 MB
  float* att    = xw;                                      // NTOK*64 floats
  float* logits = xw + (size_t)NTOK * 64;                  // NTOK*8
  float* gprob  = logits + (size_t)NTOK * E_;              // NTOK*8
  (void)ws_size; (void)in_sizes; (void)n_in; (void)out_size;

  // K0: bias projection
  biasproj_kernel<<<2, 256, 0, stream>>>(wh_bias, wh_W, bp);

  // K1: whiten  xw = x @ wh_W^T - bp
  {
    dim3 g((D_ + 63) / 64, NTOK / 64);
    gemm_nt<<<g, 256, 0, stream>>>(x, wh_W, bp, xw, NTOK, D_, DIN_);
  }
  // K2: q,k,v = xw @ W{q,k,v}^T   (N=64, K=300)
  {
    dim3 g(1, NTOK / 64);
    gemm_nt<<<g, 256, 0, stream>>>(xw, Wq, nullptr, qb, NTOK, H_ * HS_, D_);
    gemm_nt<<<g, 256, 0, stream>>>(xw, Wk, nullptr, kb, NTOK, H_ * HS_, D_);
    gemm_nt<<<g, 256, 0, stream>>>(xw, Wv, nullptr, vb, NTOK, H_ * HS_, D_);
  }
  // K3: attention (writes att, which aliases xw — xw is dead now)
  attn_kernel<<<NTOK, 64, 0, stream>>>(qb, kb, vb, att);

  // K4: xa = att @ proj_W^T + proj_b
  {
    dim3 g((D_ + 63) / 64, NTOK / 64);
    gemm_nt<<<g, 256, 0, stream>>>(att, proj_W, proj_b, xa, NTOK, D_, H_ * HS_);
  }
  // K5: gating logits
  logits_kernel<<<(NTOK * E_ + 255) / 256, 256, 0, stream>>>(xa, w_gate, logits);
  // K6: top-4 sparse softmax
  gate_kernel<<<(NTOK + 255) / 256, 256, 0, stream>>>(logits, gprob);
  // K7: fused experts + mixture + output
  expert_kernel<<<NTOK / 16, 256, 0, stream>>>(xa, gprob, exp_W1, exp_b1, exp_W2, exp_b2, (float*)d_out);
}

// Round 3
// 3410.088 us; speedup vs baseline: 3.5920x; 3.5920x over previous
//
#include <hip/hip_runtime.h>
#include <hip/hip_bf16.h>
#include <cstdint>
#include <cstddef>

#define B_   64
#define T_   300
#define DIN_ 768
#define D_   300
#define E_   8
#define H_   4
#define HS_  16
#define NTOK (B_*T_)   // 19200
#define CHUNK 4800     // token chunk for expert phase (4 chunks)

// ---------------------------------------------------------------------------
// K0: bp[o] = -sum_d wh_bias[d] * wh_W[o,d]
// ---------------------------------------------------------------------------
__global__ void biasproj_kernel(const float* __restrict__ wh_bias,
                                const float* __restrict__ wh_W,
                                float* __restrict__ bp) {
  int o = blockIdx.x * blockDim.x + threadIdx.x;
  if (o >= D_) return;
  float acc = 0.f;
  const float* row = wh_W + (size_t)o * DIN_;
  for (int d = 0; d < DIN_; ++d) acc += wh_bias[d] * row[d];
  bp[o] = -acc;
}

// ---------------------------------------------------------------------------
// Tiled GEMM: C[M,N] = A[M,K] * B[N,K]^T (+bias) with fused epilogues.
// 64x64 tile, TK=16, 256 threads, 4x4 per thread.
// LDS is k-major [16][68] so fragment reads are ds_read_b128.
// EPI: 0 = C = acc (+bias if non-null)
//      1 = C = relu(acc + bias)
//      2 = MoE first : gsum = g*eo, esum = eo        (eo = acc + bias)
//      3 = MoE mid   : gsum += g*eo, esum += eo
//      4 = MoE last  : C = (gsum + g*eo) * (esum + eo)
// ---------------------------------------------------------------------------
template<int EPI>
__global__ __launch_bounds__(256) void gemm_k(
    const float* __restrict__ A, const float* __restrict__ Bm,
    const float* __restrict__ bias, float* __restrict__ C,
    float* __restrict__ gsum, float* __restrict__ esum,
    const float* __restrict__ gate,   // per-row gate weight, stride E_
    int M, int N, int K) {
  __shared__ float As[16][68];
  __shared__ float Bs[16][68];
  const int bm = blockIdx.y * 64, bn = blockIdx.x * 64;
  const int tid = threadIdx.x;
  const int tx = tid & 15, ty = tid >> 4;
  const int r  = tid >> 2;
  const int c4 = (tid & 3) * 4;
  float acc[4][4] = {};
  for (int k0 = 0; k0 < K; k0 += 16) {
    // stage A tile (transposed into k-major)
    {
      int gr = bm + r;
      if (gr < M && k0 + c4 + 3 < K) {
        float4 v = *(const float4*)&A[(size_t)gr * K + k0 + c4];
        As[c4 + 0][r] = v.x; As[c4 + 1][r] = v.y;
        As[c4 + 2][r] = v.z; As[c4 + 3][r] = v.w;
      } else {
        #pragma unroll
        for (int u = 0; u < 4; ++u) {
          int gc = k0 + c4 + u;
          As[c4 + u][r] = (gr < M && gc < K) ? A[(size_t)gr * K + gc] : 0.f;
        }
      }
    }
    // stage B tile
    {
      int gr = bn + r;
      if (gr < N && k0 + c4 + 3 < K) {
        float4 v = *(const float4*)&Bm[(size_t)gr * K + k0 + c4];
        Bs[c4 + 0][r] = v.x; Bs[c4 + 1][r] = v.y;
        Bs[c4 + 2][r] = v.z; Bs[c4 + 3][r] = v.w;
      } else {
        #pragma unroll
        for (int u = 0; u < 4; ++u) {
          int gc = k0 + c4 + u;
          Bs[c4 + u][r] = (gr < N && gc < K) ? Bm[(size_t)gr * K + gc] : 0.f;
        }
      }
    }
    __syncthreads();
    #pragma unroll
    for (int kk = 0; kk < 16; ++kk) {
      float4 a = *(const float4*)&As[kk][ty * 4];
      float4 b = *(const float4*)&Bs[kk][tx * 4];
      float av[4] = {a.x, a.y, a.z, a.w};
      float bv[4] = {b.x, b.y, b.z, b.w};
      #pragma unroll
      for (int i = 0; i < 4; ++i)
        #pragma unroll
        for (int j = 0; j < 4; ++j) acc[i][j] += av[i] * bv[j];
    }
    __syncthreads();
  }
  #pragma unroll
  for (int i = 0; i < 4; ++i) {
    int rr = bm + ty * 4 + i;
    if (rr >= M) continue;
    float g = 0.f;
    if (EPI >= 2) g = gate[(size_t)rr * E_];
    #pragma unroll
    for (int j = 0; j < 4; ++j) {
      int cc = bn + tx * 4 + j;
      if (cc >= N) continue;
      float v = acc[i][j];
      if (EPI == 0) {
        if (bias) v += bias[cc];
        C[(size_t)rr * N + cc] = v;
      } else if (EPI == 1) {
        v = fmaxf(v + bias[cc], 0.f);
        C[(size_t)rr * N + cc] = v;
      } else {
        float eo = v + bias[cc];
        size_t idx = (size_t)rr * N + cc;
        if (EPI == 2) {
          gsum[idx] = g * eo;
          esum[idx] = eo;
        } else if (EPI == 3) {
          gsum[idx] += g * eo;
          esum[idx] += eo;
        } else {
          float gs = gsum[idx] + g * eo;
          float es = esum[idx] + eo;
          C[idx] = gs * es;
        }
      }
    }
  }
}

// ---------------------------------------------------------------------------
// Attention: one 64-thread block per (b,t). 16 lanes per head.
// ---------------------------------------------------------------------------
__global__ __launch_bounds__(64) void attn_kernel(
    const float* __restrict__ q, const float* __restrict__ k,
    const float* __restrict__ v, float* __restrict__ att) {
  const int bt = blockIdx.x;
  const int b = bt / T_, t = bt % T_;
  const int lane = threadIdx.x;
  const int h = lane >> 4, li = lane & 15;
  __shared__ float p[H_][304];
  __shared__ float qs[64];
  qs[lane] = q[(size_t)bt * 64 + lane];
  __syncthreads();
  const float scale = rsqrtf((float)D_);
  const float* kbase = k + (size_t)b * T_ * 64 + h * 16;
  float mmax = -1e30f;
  for (int s = li; s <= t; s += 16) {
    const float* kr = kbase + (size_t)s * 64;
    float acc = 0.f;
    #pragma unroll
    for (int d = 0; d < 16; ++d) acc += qs[h * 16 + d] * kr[d];
    acc *= scale;
    p[h][s] = acc;
    mmax = fmaxf(mmax, acc);
  }
  #pragma unroll
  for (int m = 8; m >= 1; m >>= 1) mmax = fmaxf(mmax, __shfl_xor(mmax, m, 16));
  float lsum = 0.f;
  for (int s = li; s <= t; s += 16) {
    float e = __expf(p[h][s] - mmax);
    p[h][s] = e;
    lsum += e;
  }
  #pragma unroll
  for (int m = 8; m >= 1; m >>= 1) lsum += __shfl_xor(lsum, m, 16);
  const float inv = 1.0f / lsum;
  const float* vcol = v + (size_t)b * T_ * 64 + h * 16 + li;
  float o = 0.f;
  for (int s = 0; s <= t; ++s) o += p[h][s] * vcol[(size_t)s * 64];
  att[(size_t)bt * 64 + lane] = o * inv;
}

// ---------------------------------------------------------------------------
// logits[n,e] = sum_d xa[n,d] * w_gate[d,e]
// ---------------------------------------------------------------------------
__global__ void logits_kernel(const float* __restrict__ xa,
                              const float* __restrict__ w_gate,
                              float* __restrict__ logits) {
  int idx = blockIdx.x * blockDim.x + threadIdx.x;
  if (idx >= NTOK * E_) return;
  int n = idx >> 3, e = idx & 7;
  const float* xr = xa + (size_t)n * D_;
  float acc = 0.f;
  for (int d = 0; d < D_; ++d) acc += xr[d] * w_gate[(size_t)d * E_ + e];
  logits[idx] = acc;
}

// ---------------------------------------------------------------------------
// top-4 sparse softmax per token (in-place safe: reads all, then writes)
// ---------------------------------------------------------------------------
__global__ void gate_kernel(const float* __restrict__ logits,
                            float* __restrict__ gprob) {
  int n = blockIdx.x * blockDim.x + threadIdx.x;
  if (n >= NTOK) return;
  float l[E_];
  #pragma unroll
  for (int e = 0; e < E_; ++e) l[e] = logits[(size_t)n * E_ + e];
  bool sel[E_] = {false, false, false, false, false, false, false, false};
  for (int kk = 0; kk < E_ / 2; ++kk) {
    int bi = -1; float bv = -1e38f;
    #pragma unroll
    for (int e = 0; e < E_; ++e)
      if (!sel[e] && l[e] > bv) { bv = l[e]; bi = e; }
    sel[bi] = true;
  }
  float mx = -1e38f;
  #pragma unroll
  for (int e = 0; e < E_; ++e) if (sel[e]) mx = fmaxf(mx, l[e]);
  float s = 0.f, pp[E_];
  #pragma unroll
  for (int e = 0; e < E_; ++e) {
    pp[e] = sel[e] ? __expf(l[e] - mx) : 0.f;
    s += pp[e];
  }
  float inv = 1.0f / s;
  #pragma unroll
  for (int e = 0; e < E_; ++e) gprob[(size_t)n * E_ + e] = pp[e] * inv;
}

// ---------------------------------------------------------------------------
extern "C" void kernel_launch(void* const* d_in, const int* in_sizes, int n_in,
                              void* d_out, int out_size, void* d_ws, size_t ws_size,
                              hipStream_t stream) {
  const float* x       = (const float*)d_in[0];
  const float* wh_bias = (const float*)d_in[1];
  const float* wh_W    = (const float*)d_in[2];
  const float* Wq      = (const float*)d_in[3];
  const float* Wk      = (const float*)d_in[4];
  const float* Wv      = (const float*)d_in[5];
  const float* proj_W  = (const float*)d_in[6];
  const float* proj_b  = (const float*)d_in[7];
  const float* exp_W1  = (const float*)d_in[8];
  const float* exp_b1  = (const float*)d_in[9];
  const float* exp_W2  = (const float*)d_in[10];
  const float* exp_b2  = (const float*)d_in[11];
  const float* w_gate  = (const float*)d_in[12];

  char* ws = (char*)d_ws;
  size_t off = 0;
  auto alloc = [&](size_t bytes) { void* p = ws + off; off += (bytes + 511) & ~(size_t)511; return p; };
  float* bp    = (float*)alloc(D_ * 4);
  float* xw    = (float*)alloc((size_t)NTOK * D_ * 4);   // 23.04 MB, multi-use region
  float* qb    = (float*)alloc((size_t)NTOK * 64 * 4);
  float* kb    = (float*)alloc((size_t)NTOK * 64 * 4);
  float* vb    = (float*)alloc((size_t)NTOK * 64 * 4);
  float* xa    = (float*)alloc((size_t)NTOK * D_ * 4);
  float* gprob = (float*)alloc((size_t)NTOK * E_ * 4);   // logits in-place -> gprob
  (void)ws_size; (void)in_sizes; (void)n_in; (void)out_size;

  // region reuse inside xw (23.04 MB):
  float* att  = xw;                                   // [NTOK,64] during attention
  float* h    = xw;                                   // [CHUNK,600] expert phase (11.52 MB)
  float* gsum = xw + (size_t)CHUNK * 600;             // [CHUNK,300] (5.76 MB)
  float* esum = gsum + (size_t)CHUNK * D_;            // [CHUNK,300] (5.76 MB)

  // K0: bias projection
  biasproj_kernel<<<2, 256, 0, stream>>>(wh_bias, wh_W, bp);

  // K1: whiten  xw = x @ wh_W^T + bp
  {
    dim3 g((D_ + 63) / 64, (NTOK + 63) / 64);
    gemm_k<0><<<g, 256, 0, stream>>>(x, wh_W, bp, xw, nullptr, nullptr, nullptr, NTOK, D_, DIN_);
  }
  // K2: q,k,v = xw @ W{q,k,v}^T
  {
    dim3 g(1, (NTOK + 63) / 64);
    gemm_k<0><<<g, 256, 0, stream>>>(xw, Wq, nullptr, qb, nullptr, nullptr, nullptr, NTOK, H_ * HS_, D_);
    gemm_k<0><<<g, 256, 0, stream>>>(xw, Wk, nullptr, kb, nullptr, nullptr, nullptr, NTOK, H_ * HS_, D_);
    gemm_k<0><<<g, 256, 0, stream>>>(xw, Wv, nullptr, vb, nullptr, nullptr, nullptr, NTOK, H_ * HS_, D_);
  }
  // K3: attention (att aliases xw; xw dead after QKV)
  attn_kernel<<<NTOK, 64, 0, stream>>>(qb, kb, vb, att);

  // K4: xa = att @ proj_W^T + proj_b
  {
    dim3 g((D_ + 63) / 64, (NTOK + 63) / 64);
    gemm_k<0><<<g, 256, 0, stream>>>(att, proj_W, proj_b, xa, nullptr, nullptr, nullptr, NTOK, D_, H_ * HS_);
  }
  // K5: gating logits (into gprob buffer)
  logits_kernel<<<(NTOK * E_ + 255) / 256, 256, 0, stream>>>(xa, w_gate, gprob);
  // K6: top-4 sparse softmax (in-place)
  gate_kernel<<<(NTOK + 255) / 256, 256, 0, stream>>>(gprob, gprob);

  // K7: experts, chunked over tokens; h/gsum/esum reuse xw region
  for (int c = 0; c < NTOK / CHUNK; ++c) {
    const int tok0 = c * CHUNK;
    const float* xa_c = xa + (size_t)tok0 * D_;
    float* out_c = (float*)d_out + (size_t)tok0 * D_;
    dim3 g1((600 + 63) / 64, CHUNK / 64);   // 10 x 75
    dim3 g2((D_ + 63) / 64, CHUNK / 64);    // 5 x 75
    for (int e = 0; e < E_; ++e) {
      const float* w1 = exp_W1 + (size_t)e * 600 * D_;
      const float* bb1 = exp_b1 + (size_t)e * 600;
      const float* w2 = exp_W2 + (size_t)e * D_ * 600;
      const float* bb2 = exp_b2 + (size_t)e * D_;
      const float* gate = gprob + (size_t)tok0 * E_ + e;
      gemm_k<1><<<g1, 256, 0, stream>>>(xa_c, w1, bb1, h, nullptr, nullptr, nullptr, CHUNK, 600, D_);
      if (e == 0)
        gemm_k<2><<<g2, 256, 0, stream>>>(h, w2, bb2, nullptr, gsum, esum, gate, CHUNK, D_, 600);
      else if (e < E_ - 1)
        gemm_k<3><<<g2, 256, 0, stream>>>(h, w2, bb2, nullptr, gsum, esum, gate, CHUNK, D_, 600);
      else
        gemm_k<4><<<g2, 256, 0, stream>>>(h, w2, bb2, out_c, gsum, esum, gate, CHUNK, D_, 600);
    }
  }
}